// Round 2
// baseline (2221.056 us; speedup 1.0000x reference)
//
#include <hip/hip_runtime.h>
#include <cstdint>

typedef __attribute__((ext_vector_type(8))) short short8;
typedef __attribute__((ext_vector_type(4))) float f32x4;

// Xb layout: [tile 2048][kk 2][cb 4][pos 324][j 8ci] bf16, 16B chunks.
// One ci-half = 4*324 = 1296 chunks = 20736 B. Tile = 41472 B.
#define HALF_CHUNKS 1296
#define TILE_SHORTS 20736 /* shorts per tile */
#define XB_BYTES ((size_t)41472 * 2048)
#define WB_OFFSET (XB_BYTES + 512)

__device__ inline unsigned short f2bf(float f) {
  uint32_t x = __builtin_bit_cast(uint32_t, f);
  uint32_t r = x + 0x7FFFu + ((x >> 16) & 1u); // RNE
  return (unsigned short)(r >> 16);
}

__device__ __forceinline__ void gl_lds16(const void* g, void* l) {
  __builtin_amdgcn_global_load_lds(
      (const __attribute__((address_space(1))) unsigned int*)g,
      (__attribute__((address_space(3))) unsigned int*)l, 16, 0, 0);
}

// ---------------- Pre-pass W: kernels (9,64,64,3,3) fp32 -> bf16 A-fragments.
// Wb chunk index g = (((kap*2+kk)*9+uv)*4+mt)*64 + lane; lane holds
// A[m = lane&15][k_half = (lane>>4)*8 + j], ci = kk*32 + k_half.
__global__ void prep_w(const float* __restrict__ K, unsigned short* __restrict__ Wb) {
  int g = blockIdx.x * 256 + threadIdx.x; // [0, 41472)
  int lane = g & 63;
  int q = g >> 6;
  int mt = q & 3; q >>= 2;
  int uv = q % 9; q /= 9;
  int kk = q & 1;
  int kap = q >> 1;
  int dy = uv / 3, dx = uv % 3;
  int co = mt * 16 + (lane & 15);
  int ci0 = kk * 32 + (lane >> 4) * 8;
  unsigned short v[8];
#pragma unroll
  for (int j = 0; j < 8; ++j)
    v[j] = f2bf(K[(((kap * 64 + co) * 64 + ci0 + j) * 3 + dy) * 3 + dx]);
  uint4 pk;
  pk.x = v[0] | ((uint32_t)v[1] << 16);
  pk.y = v[2] | ((uint32_t)v[3] << 16);
  pk.z = v[4] | ((uint32_t)v[5] << 16);
  pk.w = v[6] | ((uint32_t)v[7] << 16);
  ((uint4*)Wb)[g] = pk;
}

// ---------------- Pre-pass X: inp (8,64,256,256) fp32 -> Xb tiles with
// pre-zeroed 18x18 halo, layout [kk][cb][pos324][8ci].
__global__ __launch_bounds__(256) void prep_x(const float* __restrict__ inp,
                                              unsigned short* __restrict__ Xb) {
  __shared__ __align__(16) unsigned short xl[64][256]; // [ci][pos16x16]
  int t = threadIdx.x;
  int blk = blockIdx.x;
  int b = blk >> 8, ty = (blk >> 4) & 15, tx = blk & 15;
  const float* base = inp + (size_t)b * 64 * 65536 + (ty * 16) * 256 + tx * 16;
  // phase 1: coalesced float4 reads -> LDS [ci][pos] bf16
#pragma unroll
  for (int i = 0; i < 16; ++i) {
    int f = i * 256 + t;
    int ci = f >> 6;
    int r = f & 63;
    int iy = r >> 2, ixq = r & 3;
    const float4 v = *(const float4*)(base + (size_t)ci * 65536 + iy * 256 + ixq * 4);
    uint2 pk;
    pk.x = (uint32_t)f2bf(v.x) | ((uint32_t)f2bf(v.y) << 16);
    pk.y = (uint32_t)f2bf(v.z) | ((uint32_t)f2bf(v.w) << 16);
    *(uint2*)&xl[ci][iy * 16 + ixq * 4] = pk;
  }
  __syncthreads();
  uint4* tileo = (uint4*)(Xb + (size_t)blk * TILE_SHORTS);
  // phase 2: thread (cg = t>>5 in [0,8), pb = t&31) transposes an
  // 8ci x 8pos block: 8 x ds_read_b128 + register transpose.
  int cg = t >> 5, pb = t & 31;
  int ci0 = cg * 8, p0 = pb * 8;
  short8 rowv[8];
#pragma unroll
  for (int j = 0; j < 8; ++j) rowv[j] = *(const short8*)&xl[ci0 + j][p0];
#pragma unroll
  for (int pp = 0; pp < 8; ++pp) {
    int p = p0 + pp;
    int iy = p >> 4, ix = p & 15;
    int opos = (iy + 1) * 18 + ix + 1;
    uint4 pk;
    pk.x = (uint32_t)(unsigned short)rowv[0][pp] | ((uint32_t)(unsigned short)rowv[1][pp] << 16);
    pk.y = (uint32_t)(unsigned short)rowv[2][pp] | ((uint32_t)(unsigned short)rowv[3][pp] << 16);
    pk.z = (uint32_t)(unsigned short)rowv[4][pp] | ((uint32_t)(unsigned short)rowv[5][pp] << 16);
    pk.w = (uint32_t)(unsigned short)rowv[6][pp] | ((uint32_t)(unsigned short)rowv[7][pp] << 16);
    tileo[cg * 324 + opos] = pk;
  }
  // halo chunks: 68 halo positions x 8 cg, zeros
  for (int h = t; h < 544; h += 256) {
    int cg2 = h / 68, hi = h % 68;
    int pos;
    if (hi < 18) pos = hi;                       // top row
    else if (hi < 36) pos = 17 * 18 + (hi - 18); // bottom row
    else {
      int r2 = hi - 36;
      pos = (1 + (r2 >> 1)) * 18 + ((r2 & 1) ? 17 : 0);
    }
    tileo[cg2 * 324 + pos] = make_uint4(0u, 0u, 0u, 0u);
  }
}

// ---------------- Main: one block per output tile. Per neighbor tile, stage
// 32-ci halves (20736 B) via global_load_lds, 9 taps x 16 MFMA per half.
__global__ __launch_bounds__(256, 5) void cocov_main(const unsigned short* __restrict__ Xb,
                                                     const unsigned short* __restrict__ Wb,
                                                     float* __restrict__ out) {
  __shared__ __align__(16) unsigned short xl[HALF_CHUNKS * 8]; // 20736 B
  int t = threadIdx.x;
  int lane = t & 63, w = t >> 6;
  int n = lane & 15, quad = lane >> 4;
  int blk = blockIdx.x;
  int b = blk & 7;           // XCD swizzle: each XCD works one image
  int t2 = blk >> 3;
  int ty = t2 >> 4, tx = t2 & 15;

  f32x4 acc[4][4];
  const f32x4 zero = {0.0f, 0.0f, 0.0f, 0.0f};
#pragma unroll
  for (int i = 0; i < 4; ++i)
#pragma unroll
    for (int j = 0; j < 4; ++j) acc[i][j] = zero;

  for (int dr = -1; dr <= 1; ++dr) {
    for (int dc = -1; dc <= 1; ++dc) {
      int sy = ty + dr, sx = tx + dc;
      if (sy < 0 || sy > 15 || sx < 0 || sx > 15) continue; // block-uniform
      int kap = (dr + 1) * 3 + (dc + 1);
      const uint4* tile = (const uint4*)(Xb + (size_t)((b * 16 + sy) * 16 + sx) * TILE_SHORTS);
#pragma unroll
      for (int kk = 0; kk < 2; ++kk) {
        const uint4* half = tile + kk * HALF_CHUNKS;
        __syncthreads(); // previous compute done reading xl
#pragma unroll
        for (int it = 0; it < 5; ++it) {
          int c = it * 256 + t;
          gl_lds16(half + c, (void*)&xl[c * 8]);
        }
        if (t < 16) {
          int c = 1280 + t;
          gl_lds16(half + c, (void*)&xl[c * 8]);
        }
        __syncthreads(); // drains vmcnt -> LDS ready
        const uint4* wb = (const uint4*)Wb + (size_t)((kap * 2 + kk) * 9) * 256 + lane;
#pragma unroll
        for (int uv = 0; uv < 9; ++uv) {
          int dy = uv / 3, dx = uv % 3;
          short8 a[4];
#pragma unroll
          for (int mt = 0; mt < 4; ++mt)
            a[mt] = __builtin_bit_cast(short8, wb[uv * 256 + mt * 64]);
          short8 bfr[4];
#pragma unroll
          for (int ntl = 0; ntl < 4; ++ntl) {
            int pos = (w * 4 + ntl + dy) * 18 + (n + dx);
            bfr[ntl] = *(const short8*)&xl[(quad * 324 + pos) * 8];
          }
#pragma unroll
          for (int mt = 0; mt < 4; ++mt)
#pragma unroll
            for (int ntl = 0; ntl < 4; ++ntl)
              acc[mt][ntl] = __builtin_amdgcn_mfma_f32_16x16x32_bf16(
                  a[mt], bfr[ntl], acc[mt][ntl], 0, 0, 0);
        }
      }
    }
  }
  // epilogue: D layout row(co) = quad*4+reg, col(ix) = lane&15; iy = w*4+ntl
#pragma unroll
  for (int mt = 0; mt < 4; ++mt)
#pragma unroll
    for (int ntl = 0; ntl < 4; ++ntl) {
      int iy = w * 4 + ntl;
#pragma unroll
      for (int reg = 0; reg < 4; ++reg) {
        int co = mt * 16 + quad * 4 + reg;
        out[(((size_t)b * 64 + co) * 256 + ty * 16 + iy) * 256 + tx * 16 + n] =
            acc[mt][ntl][reg];
      }
    }
}

extern "C" void kernel_launch(void* const* d_in, const int* in_sizes, int n_in,
                              void* d_out, int out_size, void* d_ws, size_t ws_size,
                              hipStream_t stream) {
  const float* inp = (const float*)d_in[0];
  const float* ker = (const float*)d_in[1];
  unsigned short* Xb = (unsigned short*)d_ws;
  unsigned short* Wb = (unsigned short*)((char*)d_ws + WB_OFFSET);
  prep_w<<<162, 256, 0, stream>>>(ker, Wb);
  prep_x<<<2048, 256, 0, stream>>>(inp, Xb);
  cocov_main<<<2048, 256, 0, stream>>>(Xb, Wb, (float*)d_out);
}

// Round 3
// 501.927 us; speedup vs baseline: 4.4251x; 4.4251x over previous
//
#include <hip/hip_runtime.h>
#include <cstdint>

typedef __attribute__((ext_vector_type(8))) short short8;
typedef __attribute__((ext_vector_type(4))) float f32x4;

// Xb layout: [tile 2048][kk 2][cb 4][pos 324][j 8ci] bf16, 16B chunks.
// One ci-half = 4*324 = 1296 chunks = 20736 B. Tile = 41472 B.
#define HALF_CHUNKS 1296
#define TILE_SHORTS 20736 /* shorts per tile */
#define XB_BYTES ((size_t)41472 * 2048)
#define WB_OFFSET (XB_BYTES + 512)

__device__ inline unsigned short f2bf(float f) {
  uint32_t x = __builtin_bit_cast(uint32_t, f);
  uint32_t r = x + 0x7FFFu + ((x >> 16) & 1u); // RNE
  return (unsigned short)(r >> 16);
}

__device__ __forceinline__ void gl_lds16(const void* g, void* l) {
  __builtin_amdgcn_global_load_lds(
      (const __attribute__((address_space(1))) unsigned int*)g,
      (__attribute__((address_space(3))) unsigned int*)l, 16, 0, 0);
}

// ---------------- Pre-pass W: kernels (9,64,64,3,3) fp32 -> bf16 A-fragments.
// Wb chunk index g = (((kap*2+kk)*9+uv)*4+mt)*64 + lane; lane holds
// A[m = lane&15][k_half = (lane>>4)*8 + j], ci = kk*32 + k_half.
__global__ void prep_w(const float* __restrict__ K, unsigned short* __restrict__ Wb) {
  int g = blockIdx.x * 256 + threadIdx.x; // [0, 41472)
  int lane = g & 63;
  int q = g >> 6;
  int mt = q & 3; q >>= 2;
  int uv = q % 9; q /= 9;
  int kk = q & 1;
  int kap = q >> 1;
  int dy = uv / 3, dx = uv % 3;
  int co = mt * 16 + (lane & 15);
  int ci0 = kk * 32 + (lane >> 4) * 8;
  unsigned short v[8];
#pragma unroll
  for (int j = 0; j < 8; ++j)
    v[j] = f2bf(K[(((kap * 64 + co) * 64 + ci0 + j) * 3 + dy) * 3 + dx]);
  uint4 pk;
  pk.x = v[0] | ((uint32_t)v[1] << 16);
  pk.y = v[2] | ((uint32_t)v[3] << 16);
  pk.z = v[4] | ((uint32_t)v[5] << 16);
  pk.w = v[6] | ((uint32_t)v[7] << 16);
  ((uint4*)Wb)[g] = pk;
}

// ---------------- Pre-pass X: inp (8,64,256,256) fp32 -> Xb tiles with
// pre-zeroed 18x18 halo, layout [kk][cb][pos324][8ci].
__global__ __launch_bounds__(256) void prep_x(const float* __restrict__ inp,
                                              unsigned short* __restrict__ Xb) {
  __shared__ __align__(16) unsigned short xl[64][256]; // [ci][pos16x16]
  int t = threadIdx.x;
  int blk = blockIdx.x;
  int b = blk >> 8, ty = (blk >> 4) & 15, tx = blk & 15;
  const float* base = inp + (size_t)b * 64 * 65536 + (ty * 16) * 256 + tx * 16;
  // phase 1: coalesced float4 reads -> LDS [ci][pos] bf16
#pragma unroll
  for (int i = 0; i < 16; ++i) {
    int f = i * 256 + t;
    int ci = f >> 6;
    int r = f & 63;
    int iy = r >> 2, ixq = r & 3;
    const float4 v = *(const float4*)(base + (size_t)ci * 65536 + iy * 256 + ixq * 4);
    uint2 pk;
    pk.x = (uint32_t)f2bf(v.x) | ((uint32_t)f2bf(v.y) << 16);
    pk.y = (uint32_t)f2bf(v.z) | ((uint32_t)f2bf(v.w) << 16);
    *(uint2*)&xl[ci][iy * 16 + ixq * 4] = pk;
  }
  __syncthreads();
  uint4* tileo = (uint4*)(Xb + (size_t)blk * TILE_SHORTS);
  // phase 2: thread (cg = t>>5 in [0,8), pb = t&31) transposes an
  // 8ci x 8pos block: 8 x ds_read_b128 + register transpose.
  int cg = t >> 5, pb = t & 31;
  int ci0 = cg * 8, p0 = pb * 8;
  short8 rowv[8];
#pragma unroll
  for (int j = 0; j < 8; ++j) rowv[j] = *(const short8*)&xl[ci0 + j][p0];
#pragma unroll
  for (int pp = 0; pp < 8; ++pp) {
    int p = p0 + pp;
    int iy = p >> 4, ix = p & 15;
    int opos = (iy + 1) * 18 + ix + 1;
    uint4 pk;
    pk.x = (uint32_t)(unsigned short)rowv[0][pp] | ((uint32_t)(unsigned short)rowv[1][pp] << 16);
    pk.y = (uint32_t)(unsigned short)rowv[2][pp] | ((uint32_t)(unsigned short)rowv[3][pp] << 16);
    pk.z = (uint32_t)(unsigned short)rowv[4][pp] | ((uint32_t)(unsigned short)rowv[5][pp] << 16);
    pk.w = (uint32_t)(unsigned short)rowv[6][pp] | ((uint32_t)(unsigned short)rowv[7][pp] << 16);
    tileo[cg * 324 + opos] = pk;
  }
  // halo chunks: 68 halo positions x 8 cg, zeros
  for (int h = t; h < 544; h += 256) {
    int cg2 = h / 68, hi = h % 68;
    int pos;
    if (hi < 18) pos = hi;                       // top row
    else if (hi < 36) pos = 17 * 18 + (hi - 18); // bottom row
    else {
      int r2 = hi - 36;
      pos = (1 + (r2 >> 1)) * 18 + ((r2 & 1) ? 17 : 0);
    }
    tileo[cg2 * 324 + pos] = make_uint4(0u, 0u, 0u, 0u);
  }
}

// ---------------- Main: one block per output tile. Per neighbor tile, stage
// 32-ci halves (20736 B) via global_load_lds; B-row fragments deduped across
// dy (6 rows per dx instead of 12), reused for 3 MFMA groups.
__global__ __launch_bounds__(256) void cocov_main(const unsigned short* __restrict__ Xb,
                                                  const unsigned short* __restrict__ Wb,
                                                  float* __restrict__ out) {
  __shared__ __align__(16) unsigned short xl[HALF_CHUNKS * 8]; // 20736 B
  int t = threadIdx.x;
  int lane = t & 63, w = t >> 6;
  int n = lane & 15, quad = lane >> 4;
  int blk = blockIdx.x;
  int b = blk & 7; // XCD swizzle: each XCD works one image
  int t2 = blk >> 3;
  int ty = t2 >> 4, tx = t2 & 15;

  f32x4 acc[4][4];
  const f32x4 zero = {0.0f, 0.0f, 0.0f, 0.0f};
#pragma unroll
  for (int i = 0; i < 4; ++i)
#pragma unroll
    for (int j = 0; j < 4; ++j) acc[i][j] = zero;

  for (int dr = -1; dr <= 1; ++dr) {
    for (int dc = -1; dc <= 1; ++dc) {
      int sy = ty + dr, sx = tx + dc;
      if (sy < 0 || sy > 15 || sx < 0 || sx > 15) continue; // block-uniform
      int kap = (dr + 1) * 3 + (dc + 1);
      const uint4* tile = (const uint4*)(Xb + (size_t)((b * 16 + sy) * 16 + sx) * TILE_SHORTS);
#pragma unroll
      for (int kk = 0; kk < 2; ++kk) {
        const uint4* half = tile + kk * HALF_CHUNKS;
        __syncthreads(); // previous compute done reading xl
#pragma unroll
        for (int it = 0; it < 5; ++it) {
          int c = it * 256 + t;
          gl_lds16(half + c, (void*)&xl[c * 8]);
        }
        if (t < 16) {
          int c = 1280 + t;
          gl_lds16(half + c, (void*)&xl[c * 8]);
        }
        __syncthreads(); // drains vmcnt -> LDS ready
        const uint4* wb = (const uint4*)Wb + (size_t)((kap * 2 + kk) * 9) * 256 + lane;
#pragma unroll
        for (int dx = 0; dx < 3; ++dx) {
          // 6 distinct row-chunks cover ntl+dy for ntl 0..3, dy 0..2
          short8 r[6];
#pragma unroll
          for (int j = 0; j < 6; ++j) {
            int pos = (w * 4 + j) * 18 + (n + dx);
            r[j] = *(const short8*)&xl[(quad * 324 + pos) * 8];
          }
#pragma unroll
          for (int dy = 0; dy < 3; ++dy) {
            int uv = dy * 3 + dx;
            short8 a[4];
#pragma unroll
            for (int mt = 0; mt < 4; ++mt)
              a[mt] = __builtin_bit_cast(short8, wb[uv * 256 + mt * 64]);
#pragma unroll
            for (int mt = 0; mt < 4; ++mt)
#pragma unroll
              for (int ntl = 0; ntl < 4; ++ntl)
                acc[mt][ntl] = __builtin_amdgcn_mfma_f32_16x16x32_bf16(
                    a[mt], r[ntl + dy], acc[mt][ntl], 0, 0, 0);
          }
        }
      }
    }
  }
  // epilogue: D layout row(co) = quad*4+reg, col(ix) = lane&15; iy = w*4+ntl
#pragma unroll
  for (int mt = 0; mt < 4; ++mt)
#pragma unroll
    for (int ntl = 0; ntl < 4; ++ntl) {
      int iy = w * 4 + ntl;
#pragma unroll
      for (int reg = 0; reg < 4; ++reg) {
        int co = mt * 16 + quad * 4 + reg;
        out[(((size_t)b * 64 + co) * 256 + ty * 16 + iy) * 256 + tx * 16 + n] =
            acc[mt][ntl][reg];
      }
    }
}

extern "C" void kernel_launch(void* const* d_in, const int* in_sizes, int n_in,
                              void* d_out, int out_size, void* d_ws, size_t ws_size,
                              hipStream_t stream) {
  const float* inp = (const float*)d_in[0];
  const float* ker = (const float*)d_in[1];
  unsigned short* Xb = (unsigned short*)d_ws;
  unsigned short* Wb = (unsigned short*)((char*)d_ws + WB_OFFSET);
  prep_w<<<162, 256, 0, stream>>>(ker, Wb);
  prep_x<<<2048, 256, 0, stream>>>(inp, Xb);
  cocov_main<<<2048, 256, 0, stream>>>(Xb, Wb, (float*)d_out);
}